// Round 1
// 925.121 us; speedup vs baseline: 1.0206x; 1.0206x over previous
//
#include <hip/hip_runtime.h>

#define NMUL 16
#define NSTEP 365
#define NGRID 10000
#define NEARZERO 1e-5f
#define UNROLL 5          // 365 = 5*73 exactly — no tail step

// One thread per (grid, mul) chain; m = tid & 15, g = tid >> 4.
// Kernel is VALU-issue-bound at 2.44 waves/SIMD -> minimize dynamic
// instructions per step: native exp2/log2 pow, fused DPP rotate-accumulate
// reduction (no ds_swizzle / lgkm waits), 32-bit addressing, 5-step bodies.

__device__ __forceinline__ float fast_pow(float x, float y) {
    // x > 0 guaranteed (SM >= NEARZERO, FC >= 50).
#if __has_builtin(__builtin_amdgcn_exp2f) && __has_builtin(__builtin_amdgcn_logf)
    // v_log_f32 is log2, v_exp_f32 is exp2 -> no ln2 fixup multiplies.
    return __builtin_amdgcn_exp2f(y * __builtin_amdgcn_logf(x));
#else
    return __expf(y * __logf(x));
#endif
}

struct HbvP {
    float parBETA, parK0, parBETAET;
    float parFC, parK1, parK2, parLP, parPERC, parUZL, parTT,
          parCFMAX, parCWH, parC, parCFR;
    float invFC, invLPFC, regional_flow;
};

__device__ __forceinline__ float hbv_step(
    float Pm, float Tm, float PETm,
    float& SNOWPACK, float& MELTWATER, float& SM, float& SUZ, float& SLZ,
    const HbvP& p)
{
    // snow routine
    const float d    = Tm - p.parTT;                 // sign(d) == sign(Tm - TT)
    const float RAIN = (d >= 0.0f) ? Pm : 0.0f;
    const float SNOW = Pm - RAIN;
    SNOWPACK += SNOW;
    const float md   = p.parCFMAX * d;               // reused for melt AND refreeze
    const float melt = fminf(fmaxf(md, 0.0f), SNOWPACK);
    MELTWATER += melt;
    SNOWPACK  -= melt;
    const float refreezing = fminf(p.parCFR * fmaxf(-md, 0.0f), MELTWATER);
    SNOWPACK  += refreezing;
    MELTWATER -= refreezing;
    const float tosoil = fmaxf(MELTWATER - p.parCWH * SNOWPACK, 0.0f);
    MELTWATER -= tosoil;

    // soil routine
    const float soil_wetness = fminf(fast_pow(SM * p.invFC, p.parBETA), 1.0f);
    const float rt = RAIN + tosoil;
    const float recharge = rt * soil_wetness;
    SM = SM + rt - recharge;
    const float excess = fmaxf(SM - p.parFC, 0.0f);
    SM -= excess;
    const float evapfactor = fminf(fast_pow(SM * p.invLPFC, p.parBETAET), 1.0f);
    const float ETact = fminf(SM, PETm * evapfactor);
    SM = fmaxf(SM - ETact, NEARZERO);
    const float capillary = fminf(SLZ, p.parC * SLZ * (1.0f - fminf(SM * p.invFC, 1.0f)));
    SM  = fmaxf(SM + capillary, NEARZERO);
    SLZ = fmaxf(SLZ - capillary, NEARZERO);

    // response routine
    SUZ = SUZ + recharge + excess;
    const float PERCa = fminf(SUZ, p.parPERC);
    SUZ -= PERCa;
    const float Q0 = p.parK0 * fmaxf(SUZ - p.parUZL, 0.0f);
    SUZ -= Q0;
    const float Q1 = p.parK1 * SUZ;
    SUZ -= Q1;
    SLZ += PERCa;
    SLZ = fmaxf(SLZ + p.regional_flow, 0.0f);
    const float Q2 = p.parK2 * SLZ;
    SLZ -= Q2;

    return Q0 + Q1 + Q2;
}

__global__ __launch_bounds__(256) void hbv_kernel(
    const float* __restrict__ x,   // (NSTEP, NGRID, 3)  P,T,PET
    const float* __restrict__ pr,  // (NSTEP, NGRID, 3, NMUL) — only [-1] used
    const float* __restrict__ wl,  // (NGRID, 13, NMUL)
    const float* __restrict__ ac,  // (NGRID,)
    float* __restrict__ out)       // (NSTEP, NGRID)
{
    const int tid = blockIdx.x * blockDim.x + threadIdx.x;  // grid*block == NGRID*NMUL exactly
    const int g = tid >> 4;
    const int m = tid & 15;

    HbvP p;
    // ---- HBV params from params_raw[NSTEP-1, g, i, m] ---- (fits 32-bit: <2^31)
    const unsigned pbase = ((unsigned)(NSTEP - 1) * NGRID + (unsigned)g) * (3u * NMUL) + (unsigned)m;
    p.parBETA   = 1.0f  + pr[pbase + 0u * NMUL] * 5.0f;
    p.parK0     = 0.05f + pr[pbase + 1u * NMUL] * 0.85f;
    p.parBETAET = 0.3f  + pr[pbase + 2u * NMUL] * 4.7f;

    // ---- Waterloss params from wl[g, i, m] ----
    const unsigned wbase = (unsigned)g * (13u * NMUL) + (unsigned)m;
    p.parFC    = 50.0f  + wl[wbase +  0u * NMUL] * 950.0f;
    p.parK1    = 0.01f  + wl[wbase +  1u * NMUL] * 0.49f;
    p.parK2    = 0.001f + wl[wbase +  2u * NMUL] * 0.199f;
    p.parLP    = 0.2f   + wl[wbase +  3u * NMUL] * 0.8f;
    p.parPERC  =          wl[wbase +  4u * NMUL] * 10.0f;
    p.parUZL   =          wl[wbase +  5u * NMUL] * 100.0f;
    p.parTT    = -2.5f  + wl[wbase +  6u * NMUL] * 5.0f;
    p.parCFMAX = 0.5f   + wl[wbase +  7u * NMUL] * 9.5f;
    p.parCFR   =          wl[wbase +  8u * NMUL] * 0.1f;
    p.parCWH   =          wl[wbase +  9u * NMUL] * 0.2f;
    p.parC     =          wl[wbase + 10u * NMUL] * 1.0f;
    const float parTR  =  wl[wbase + 11u * NMUL] * 20.0f;
    const float parAc  =  wl[wbase + 12u * NMUL] * 2500.0f;

    // ---- regional_flow (time-invariant) ----
    const float acm = ac[g];
    if (acm < 2500.0f) {
        float rf = fminf(fmaxf((acm - parAc) * 0.001f, -1.0f), 1.0f);
        p.regional_flow = rf * parTR;
    } else {
        float e = fminf(fmaxf(-(acm - 2500.0f) * 0.02f, -10.0f), 0.0f);
        p.regional_flow = __expf(e) * parTR;
    }

    p.invFC   = 1.0f / p.parFC;
    p.invLPFC = 1.0f / (p.parLP * p.parFC);

    float SNOWPACK = 0.001f, MELTWATER = 0.001f, SM = 0.001f, SUZ = 0.001f, SLZ = 0.001f;

    // ---- software-pipelined main loop: 73 bodies of 5 steps, no tail ----
    // 32-bit element offsets throughout (max x-index 365*10000*3 < 2^31).
    unsigned xoff = (unsigned)g * 3u;     // x[t=0, g, 0]
    unsigned ooff = (unsigned)g;          // out[t=0, g]

    float P0[UNROLL], T0[UNROLL], E0[UNROLL];
    #pragma unroll
    for (int u = 0; u < UNROLL; ++u) {
        const unsigned xi = xoff + (unsigned)(u * NGRID * 3);
        P0[u] = x[xi + 0u]; T0[u] = x[xi + 1u]; E0[u] = x[xi + 2u];
    }
    xoff += (unsigned)(UNROLL * NGRID * 3);

    for (int blk = 0; blk < 73; ++blk) {
        float P1[UNROLL], T1[UNROLL], E1[UNROLL];
        if (blk < 72) {   // prefetch next body's forcing — consumed a full body later
            #pragma unroll
            for (int u = 0; u < UNROLL; ++u) {
                const unsigned xi = xoff + (unsigned)(u * NGRID * 3);
                P1[u] = x[xi + 0u]; T1[u] = x[xi + 1u]; E1[u] = x[xi + 2u];
            }
        } else {
            #pragma unroll
            for (int u = 0; u < UNROLL; ++u) { P1[u] = 0.f; T1[u] = 0.f; E1[u] = 0.f; }
        }
        xoff += (unsigned)(UNROLL * NGRID * 3);

        float q[UNROLL];
        #pragma unroll
        for (int u = 0; u < UNROLL; ++u)
            q[u] = hbv_step(P0[u], T0[u], E0[u], SNOWPACK, MELTWATER, SM, SUZ, SLZ, p);

        // Fused DPP rotate-accumulate: within each 16-lane row,
        // q += ror(q,1); q += ror(q,2); q += ror(q,4); q += ror(q,8)
        // leaves the full 16-lane sum in every lane. 5 interleaved trees in one
        // asm block: >=4-inst spacing covers the VALU-write -> DPP-read hazard;
        // leading s_nop 3 guards the first reads against the q[] producers.
        asm("s_nop 3\n\t"
            "v_add_f32 %0, %0, %0 row_ror:1 row_mask:0xf bank_mask:0xf\n\t"
            "v_add_f32 %1, %1, %1 row_ror:1 row_mask:0xf bank_mask:0xf\n\t"
            "v_add_f32 %2, %2, %2 row_ror:1 row_mask:0xf bank_mask:0xf\n\t"
            "v_add_f32 %3, %3, %3 row_ror:1 row_mask:0xf bank_mask:0xf\n\t"
            "v_add_f32 %4, %4, %4 row_ror:1 row_mask:0xf bank_mask:0xf\n\t"
            "v_add_f32 %0, %0, %0 row_ror:2 row_mask:0xf bank_mask:0xf\n\t"
            "v_add_f32 %1, %1, %1 row_ror:2 row_mask:0xf bank_mask:0xf\n\t"
            "v_add_f32 %2, %2, %2 row_ror:2 row_mask:0xf bank_mask:0xf\n\t"
            "v_add_f32 %3, %3, %3 row_ror:2 row_mask:0xf bank_mask:0xf\n\t"
            "v_add_f32 %4, %4, %4 row_ror:2 row_mask:0xf bank_mask:0xf\n\t"
            "v_add_f32 %0, %0, %0 row_ror:4 row_mask:0xf bank_mask:0xf\n\t"
            "v_add_f32 %1, %1, %1 row_ror:4 row_mask:0xf bank_mask:0xf\n\t"
            "v_add_f32 %2, %2, %2 row_ror:4 row_mask:0xf bank_mask:0xf\n\t"
            "v_add_f32 %3, %3, %3 row_ror:4 row_mask:0xf bank_mask:0xf\n\t"
            "v_add_f32 %4, %4, %4 row_ror:4 row_mask:0xf bank_mask:0xf\n\t"
            "v_add_f32 %0, %0, %0 row_ror:8 row_mask:0xf bank_mask:0xf\n\t"
            "v_add_f32 %1, %1, %1 row_ror:8 row_mask:0xf bank_mask:0xf\n\t"
            "v_add_f32 %2, %2, %2 row_ror:8 row_mask:0xf bank_mask:0xf\n\t"
            "v_add_f32 %3, %3, %3 row_ror:8 row_mask:0xf bank_mask:0xf\n\t"
            "v_add_f32 %4, %4, %4 row_ror:8 row_mask:0xf bank_mask:0xf"
            : "+v"(q[0]), "+v"(q[1]), "+v"(q[2]), "+v"(q[3]), "+v"(q[4]));

        if (m == 0) {
            #pragma unroll
            for (int u = 0; u < UNROLL; ++u)
                out[ooff + (unsigned)(u * NGRID)] = q[u] * 0.0625f;
        }
        ooff += (unsigned)(UNROLL * NGRID);

        #pragma unroll
        for (int u = 0; u < UNROLL; ++u) { P0[u] = P1[u]; T0[u] = T1[u]; E0[u] = E1[u]; }
    }
}

extern "C" void kernel_launch(void* const* d_in, const int* in_sizes, int n_in,
                              void* d_out, int out_size, void* d_ws, size_t ws_size,
                              hipStream_t stream) {
    const float* x  = (const float*)d_in[0];
    const float* pr = (const float*)d_in[1];
    const float* wl = (const float*)d_in[2];
    const float* ac = (const float*)d_in[3];
    float* out = (float*)d_out;

    const int total = NGRID * NMUL;            // 160,000 threads
    const int block = 256;
    const int grid = (total + block - 1) / block;  // 625 blocks, exact
    hbv_kernel<<<grid, block, 0, stream>>>(x, pr, wl, ac, out);
}